// Round 3
// baseline (63229.950 us; speedup 1.0000x reference)
//
#include <hip/hip_runtime.h>
#include <math.h>

// Problem constants (match reference)
#define BATCH  256
#define SEQT   256
#define FEATD  256
#define NHEADS 8
#define HD     32
#define HID    512
#define GATES  2048           // 4*HID
#define BH     (BATCH*HID)    // 131072 floats per [B,HID] slab
#define TOUT   (SEQT-1)       // 255 output time steps
#define NBLK   256

__device__ __forceinline__ float sigm(float x)     { return 1.f / (1.f + __expf(-x)); }
__device__ __forceinline__ float tanhfast(float x) { return 1.f - 2.f / (1.f + __expf(2.f * x)); }

// ---------------------------------------------------------------------------
// Fused per-(n,h) attention (unchanged from round 2, verified).
// Output T-MAJOR: attn_t[t][n][f].
// ---------------------------------------------------------------------------
__global__ __launch_bounds__(256) void k_attn(
    const float* __restrict__ x,  const float* __restrict__ wq,
    const float* __restrict__ wk, const float* __restrict__ wv,
    float* __restrict__ attn_t)
{
    __shared__ float Ks[128][40];
    __shared__ float Vs[128][40];

    const int nb  = blockIdx.x;
    const int n   = nb >> 3, h = nb & 7;
    const int tid = threadIdx.x;
    const float* xbase = x + ((size_t)n * SEQT) * FEATD + h * HD;

    float qv[HD];
    {
        float xr[HD];
        const float4* xp = (const float4*)(xbase + (size_t)tid * FEATD);
        #pragma unroll
        for (int q4 = 0; q4 < 8; ++q4) {
            float4 v = xp[q4];
            xr[q4*4+0] = v.x; xr[q4*4+1] = v.y; xr[q4*4+2] = v.z; xr[q4*4+3] = v.w;
        }
        #pragma unroll
        for (int d = 0; d < HD; ++d) {
            float s = 0.f;
            #pragma unroll
            for (int e = 0; e < HD; ++e) s += xr[e] * wq[d*HD + e];
            qv[d] = s * 0.0625f;
        }
    }

    float o[HD];
    #pragma unroll
    for (int d = 0; d < HD; ++d) o[d] = 0.f;
    float m = -1e30f, ssum = 0.f;

    for (int tile = 0; tile < 2; ++tile) {
        const int j0 = tile * 128;
        __syncthreads();
        {
            const int r = tid & 127;
            const float* W = (tid < 128) ? wk : wv;
            float xt[HD];
            const float4* xp = (const float4*)(xbase + (size_t)(j0 + r) * FEATD);
            #pragma unroll
            for (int q4 = 0; q4 < 8; ++q4) {
                float4 v = xp[q4];
                xt[q4*4+0] = v.x; xt[q4*4+1] = v.y; xt[q4*4+2] = v.z; xt[q4*4+3] = v.w;
            }
            float outr[HD];
            #pragma unroll
            for (int d = 0; d < HD; ++d) {
                float s = 0.f;
                #pragma unroll
                for (int e = 0; e < HD; ++e) s += xt[e] * W[d*HD + e];
                outr[d] = s;
            }
            float (*dst)[40] = (tid < 128) ? Ks : Vs;
            #pragma unroll
            for (int d = 0; d < HD; ++d) dst[r][d] = outr[d];
        }
        __syncthreads();

        for (int j = 0; j < 128; ++j) {
            float e = 0.f;
            #pragma unroll
            for (int dq = 0; dq < 8; ++dq) {
                float4 kq = *(const float4*)&Ks[j][dq*4];
                e += qv[dq*4+0]*kq.x + qv[dq*4+1]*kq.y
                   + qv[dq*4+2]*kq.z + qv[dq*4+3]*kq.w;
            }
            if (e > m) {
                float sc = __expf(m - e);
                ssum *= sc;
                #pragma unroll
                for (int d = 0; d < HD; ++d) o[d] *= sc;
                m = e;
            }
            float p = __expf(e - m);
            ssum += p;
            #pragma unroll
            for (int dq = 0; dq < 8; ++dq) {
                float4 vq = *(const float4*)&Vs[j][dq*4];
                o[dq*4+0] += p * vq.x; o[dq*4+1] += p * vq.y;
                o[dq*4+2] += p * vq.z; o[dq*4+3] += p * vq.w;
            }
        }
    }

    const float inv = 1.f / ssum;
    float* ob = attn_t + ((size_t)tid * BATCH + n) * FEATD + h * HD;
    #pragma unroll
    for (int dq = 0; dq < 8; ++dq) {
        float4 v;
        v.x = o[dq*4+0]*inv; v.y = o[dq*4+1]*inv;
        v.z = o[dq*4+2]*inv; v.w = o[dq*4+3]*inv;
        *(float4*)&ob[dq*4] = v;
    }
}

// ---------------------------------------------------------------------------
// Wc = w_hid @ w_fc [512,256]; bc = w_hid @ b_fc + b_hid  (unchanged)
// ---------------------------------------------------------------------------
__global__ __launch_bounds__(256) void k_wcomb(
    const float* __restrict__ w_fc,  const float* __restrict__ b_fc,
    const float* __restrict__ w_hid, const float* __restrict__ b_hid,
    float* __restrict__ Wc, float* __restrict__ bc)
{
    const int i = blockIdx.x, j = threadIdx.x;
    float s = 0.f;
    for (int k = 0; k < FEATD; ++k) s += w_hid[i*FEATD + k] * w_fc[k*FEATD + j];
    Wc[(size_t)i*FEATD + j] = s;
    if (j == 0) {
        float t = b_hid[i];
        for (int k = 0; k < FEATD; ++k) t += w_hid[i*FEATD + k] * b_fc[k];
        bc[i] = t;
    }
}

// ---------------------------------------------------------------------------
// Wx0 = W_ih[0] @ Wc [2048,256]; bx0 = W_ih[0] @ bc + b_ih[0] + b_hh[0]
// (unchanged)
// ---------------------------------------------------------------------------
__global__ __launch_bounds__(256) void k_wx0(
    const float* __restrict__ w_ih, const float* __restrict__ Wc,
    const float* __restrict__ bc,   const float* __restrict__ b_ih,
    const float* __restrict__ b_hh,
    float* __restrict__ Wx0, float* __restrict__ bx0)
{
    const int i = blockIdx.x, j = threadIdx.x;
    float s = 0.f;
    for (int k = 0; k < HID; ++k) s += w_ih[(size_t)i*HID + k] * Wc[(size_t)k*FEATD + j];
    Wx0[(size_t)i*FEATD + j] = s;
    if (j == 0) {
        float t = b_ih[i] + b_hh[i];
        for (int k = 0; k < HID; ++k) t += w_ih[(size_t)i*HID + k] * bc[k];
        bx0[i] = t;
    }
}

// ---------------------------------------------------------------------------
// Device-scope grid barrier (monotonic counter, sense-free).
// Release: __threadfence() (agent acq_rel -> L2 writeback) before arrive;
// Acquire: __threadfence() (L2 invalidate) after the count is reached.
// ---------------------------------------------------------------------------
__device__ __forceinline__ void grid_bar(int* bar, int target)
{
    __syncthreads();
    if (threadIdx.x == 0) {
        __threadfence();
        __hip_atomic_fetch_add(bar, 1, __ATOMIC_RELEASE, __HIP_MEMORY_SCOPE_AGENT);
        while (__hip_atomic_load(bar, __ATOMIC_RELAXED, __HIP_MEMORY_SCOPE_AGENT) < target)
            __builtin_amdgcn_s_sleep(2);
        __threadfence();
    }
    __syncthreads();
}

// ---------------------------------------------------------------------------
// Persistent cooperative LSTM: 256 blocks (1/CU), 256 threads.
// Blocks [0,128): layer1, own 4 h-cols (hc0=b*4); weights [k][16] in LDS
//   (K=1024: Wih1 | Whh1), 64KB.
// Blocks [128,256): layer0, own 4 h-cols; weights K=768 (Wx0 | Whh0), 48KB.
// Per step: GEMM 256 rows x 16 gate-cols, A-tiles (256x32) double-buffered
// in LDS with XOR swizzle; thread = (c4=tid&3 h-col, r4=(tid>>2)*4 rows),
// acc[4 rows][4 gates]. One grid barrier per step.
// Fused projection: layer1 block b projects rows 2b,2b+1 of relu(h1(t-1))
// from its staged ph1 tiles; tail step (t=254) projected at the end.
// ---------------------------------------------------------------------------
__global__ __launch_bounds__(256) void k_lstm(
    const float* __restrict__ attn_t, const float* __restrict__ Wx0,
    const float* __restrict__ bx0,
    float* __restrict__ h0, float* __restrict__ h1,
    float* __restrict__ c0, float* __restrict__ c1,
    const float* __restrict__ w_ih, const float* __restrict__ w_hh,
    const float* __restrict__ b_ih, const float* __restrict__ b_hh,
    const float* __restrict__ w_out, const float* __restrict__ b_out,
    float* __restrict__ out, int* __restrict__ bar)
{
    extern __shared__ float smem[];
    float* wl  = smem;               // [1024][16] k-major gate weights
    float* Asm = smem + 16*1024;     // 2 x (256x32) swizzled A tiles

    const int tid  = threadIdx.x;
    const bool lay1 = (blockIdx.x < 128);
    const int b    = lay1 ? blockIdx.x : blockIdx.x - 128;
    const int hc0  = b * 4;
    const int c4   = tid & 3;
    const int r4   = (tid >> 2) << 2;      // 4-row base, 0..252
    const int hc   = hc0 + c4;
    const int scol = tid & 31;             // staging column (fixed)
    const int srow0= tid >> 5;             // staging row base (0..7)
    const int prow = 2*b + (tid >> 3);     // projection row (tid<16 only)
    const int pj   = tid & 7;              // projection output col

    // ---- stage weights into LDS, k-major: wl[k*16 + c4s*4 + g]
    if (lay1) {
        const float* wih1 = w_ih + (size_t)GATES * HID;
        const float* whh1 = w_hh + (size_t)GATES * HID;
        for (int e = tid; e < 16*1024; e += 256) {
            const int gcl = e >> 10, k = e & 1023;
            const int c4s = gcl >> 2, g = gcl & 3;
            const int grow = g*HID + hc0 + c4s;
            const float v = (k < HID) ? wih1[(size_t)grow*HID + k]
                                      : whh1[(size_t)grow*HID + (k - HID)];
            wl[k*16 + gcl] = v;
        }
    } else {
        for (int gcl = 0; gcl < 16; ++gcl) {
            const int c4s = gcl >> 2, g = gcl & 3;
            const int grow = g*HID + hc0 + c4s;
            for (int k = tid; k < 768; k += 256) {
                const float v = (k < FEATD) ? Wx0[(size_t)grow*FEATD + k]
                                            : w_hh[(size_t)grow*HID + (k - FEATD)];
                wl[k*16 + gcl] = v;
            }
        }
    }

    // ---- zero own c columns (block-private, no cross-block dependency)
    {
        float* cb = lay1 ? c1 : c0;
        #pragma unroll
        for (int i = 0; i < 4; ++i)
            cb[(size_t)(r4 + i) * HID + hc] = 0.f;
    }

    // ---- per-thread constant biases
    float bsum[4];
    if (lay1) {
        #pragma unroll
        for (int g = 0; g < 4; ++g)
            bsum[g] = b_ih[GATES + g*HID + hc] + b_hh[GATES + g*HID + hc];
    } else {
        #pragma unroll
        for (int g = 0; g < 4; ++g)
            bsum[g] = bx0[g*HID + hc];
    }
    __syncthreads();

    auto stage_load = [&](const float* src, int stride, int kloc, float* sreg) {
        #pragma unroll
        for (int q = 0; q < 32; ++q)
            sreg[q] = src[(size_t)(q*8 + srow0) * stride + kloc + scol];
    };
    auto stage_write = [&](int buf, const float* sreg) {
        #pragma unroll
        for (int q = 0; q < 32; ++q) {
            const int r = q*8 + srow0;
            Asm[(buf << 13) + (r << 5) + (scol ^ (r & 31))] = sreg[q];
        }
    };

    // one LSTM half-step: gates = A0@W[:,0:nt0*32] + A1@W[:,...], nonlin, out
    auto do_step = [&](const float* s0, int st0, int nt0,
                       const float* s1, int st1, int nt1,
                       float* cb, float* ho, bool doproj, int tout) {
        const int NT = nt0 + nt1;
        float acc[4][4] = {{0.f,0.f,0.f,0.f},{0.f,0.f,0.f,0.f},
                           {0.f,0.f,0.f,0.f},{0.f,0.f,0.f,0.f}};
        float yacc = 0.f;
        float sreg[32];

        stage_load(s0, st0, 0, sreg);
        stage_write(0, sreg);
        __syncthreads();

        for (int kt = 0; kt < NT; ++kt) {
            const int cur = kt & 1;
            if (kt + 1 < NT) {                       // issue next-tile loads early
                const int k2 = kt + 1;
                if (k2 < nt0) stage_load(s0, st0, k2*32, sreg);
                else          stage_load(s1, st1, (k2 - nt0)*32, sreg);
            }
            const int kb = kt * 32;
            const float* asb = &Asm[cur << 13];
            #pragma unroll
            for (int kk = 0; kk < 32; ++kk) {
                const float4 w4 = *(const float4*)&wl[(kb + kk)*16 + c4*4];
                #pragma unroll
                for (int i = 0; i < 4; ++i) {
                    const int r = r4 + i;
                    const float a = asb[(r << 5) + (kk ^ (r & 31))];
                    acc[i][0] += a * w4.x;
                    acc[i][1] += a * w4.y;
                    acc[i][2] += a * w4.z;
                    acc[i][3] += a * w4.w;
                }
            }
            if (doproj && kt >= nt0 && tid < 16) {   // project relu(h1(t-1))
                const int kg = (kt - nt0) * 32;
                float ya = 0.f;
                #pragma unroll
                for (int kk = 0; kk < 32; ++kk) {
                    float hv = asb[(prow << 5) + (kk ^ (prow & 31))];
                    hv = hv > 0.f ? hv : 0.f;
                    ya += hv * w_out[(size_t)pj*HID + kg + kk];
                }
                yacc += ya;
            }
            if (kt + 1 < NT) stage_write(cur ^ 1, sreg);
            __syncthreads();
        }

        #pragma unroll
        for (int i = 0; i < 4; ++i) {
            const size_t idx = (size_t)(r4 + i) * HID + hc;
            const float gi = sigm(acc[i][0] + bsum[0]);
            const float gf = sigm(acc[i][1] + bsum[1]);
            const float gg = tanhfast(acc[i][2] + bsum[2]);
            const float go = sigm(acc[i][3] + bsum[3]);
            const float cn = gf * cb[idx] + gi * gg;
            cb[idx] = cn;
            ho[idx] = go * tanhfast(cn);
        }
        if (doproj && tid < 16)
            out[(size_t)prow*(TOUT*NHEADS) + (size_t)tout*NHEADS + pj] = yacc + b_out[pj];
    };

    // ---- prologue: layer0 computes t=0 (h0(-1)=0 -> skip recurrent phase)
    if (!lay1)
        do_step(attn_t, FEATD, 8, (const float*)0, 0, 0, c0, h0, false, 0);
    grid_bar(bar, 1*NBLK);

    // ---- pipelined steps: layer1(t) || layer0(t+1)
    for (int t = 0; t <= SEQT-2; ++t) {
        if (lay1) {
            do_step(h0 + (size_t)(t & 1) * BH, HID, 16,
                    h1 + (size_t)((t & 1) ^ 1) * BH, HID, (t == 0) ? 0 : 16,
                    c1, h1 + (size_t)(t & 1) * BH, t >= 1, t - 1);
        } else if (t < SEQT-2) {
            const int tt = t + 1;
            do_step(attn_t + (size_t)tt * BATCH * FEATD, FEATD, 8,
                    h0 + (size_t)(t & 1) * BH, HID, 16,
                    c0, h0 + (size_t)(tt & 1) * BH, false, 0);
        }
        grid_bar(bar, (2 + t)*NBLK);
    }

    // ---- tail projection: h1(254) lives in parity-0 slab
    if (lay1 && tid < 16) {
        float s = b_out[pj];
        const float* hrow = h1 + (size_t)prow * HID;
        for (int k = 0; k < HID; ++k) {
            float hv = hrow[k];
            hv = hv > 0.f ? hv : 0.f;
            s += hv * w_out[(size_t)pj*HID + k];
        }
        out[(size_t)prow*(TOUT*NHEADS) + (size_t)(TOUT-1)*NHEADS + pj] = s;
    }
}

// ---------------------------------------------------------------------------
extern "C" void kernel_launch(void* const* d_in, const int* in_sizes, int n_in,
                              void* d_out, int out_size, void* d_ws, size_t ws_size,
                              hipStream_t stream)
{
    (void)in_sizes; (void)n_in; (void)out_size; (void)ws_size;
    const float* x     = (const float*)d_in[0];
    const float* wq    = (const float*)d_in[1];
    const float* wk    = (const float*)d_in[2];
    const float* wv    = (const float*)d_in[3];
    const float* w_fc  = (const float*)d_in[4];
    const float* b_fc  = (const float*)d_in[5];
    const float* w_hid = (const float*)d_in[6];
    const float* b_hid = (const float*)d_in[7];
    const float* w_ih  = (const float*)d_in[8];
    const float* w_hh  = (const float*)d_in[9];
    const float* b_ih  = (const float*)d_in[10];
    const float* b_hh  = (const float*)d_in[11];
    const float* w_out = (const float*)d_in[12];
    const float* b_out = (const float*)d_in[13];

    float* ws = (float*)d_ws;
    size_t off = 0;
    float* attn_t = ws + off; off += (size_t)SEQT * BATCH * FEATD;  // 16.78M
    float* Wc     = ws + off; off += (size_t)HID * FEATD;
    float* bc     = ws + off; off += HID;
    float* Wx0    = ws + off; off += (size_t)GATES * FEATD;
    float* bx0    = ws + off; off += GATES;
    float* h0     = ws + off; off += 2 * (size_t)BH;
    float* h1     = ws + off; off += 2 * (size_t)BH;
    float* c0     = ws + off; off += (size_t)BH;
    float* c1     = ws + off; off += (size_t)BH;
    int*   bar    = (int*)(ws + off); off += 64;
    // total ~18.4M floats = ~73.4 MB

    hipMemsetAsync(bar, 0, sizeof(int), stream);

    k_attn  <<<dim3(BATCH*NHEADS), dim3(256), 0, stream>>>(x, wq, wk, wv, attn_t);
    k_wcomb <<<dim3(HID),          dim3(256), 0, stream>>>(w_fc, b_fc, w_hid, b_hid, Wc, bc);
    k_wx0   <<<dim3(GATES),        dim3(256), 0, stream>>>(w_ih, Wc, bc, b_ih, b_hh, Wx0, bx0);

    const size_t shmem = (size_t)(16*1024 + 2*256*32) * sizeof(float);  // 131072 B
    (void)hipFuncSetAttribute(reinterpret_cast<const void*>(k_lstm),
                              hipFuncAttributeMaxDynamicSharedMemorySize,
                              (int)shmem);
    k_lstm <<<dim3(NBLK), dim3(256), shmem, stream>>>(
        attn_t, Wx0, bx0, h0, h1, c0, c1,
        w_ih, w_hh, b_ih, b_hh, w_out, b_out, (float*)d_out, bar);
}

// Round 4
// 23247.354 us; speedup vs baseline: 2.7199x; 2.7199x over previous
//
#include <hip/hip_runtime.h>
#include <math.h>

// Problem constants
#define BATCH  256
#define SEQT   256
#define FEATD  256
#define NHEADS 8
#define HD     32
#define HID    512
#define GATES  2048
#define BH     (BATCH*HID)       // elems per [B,HID] slab
#define TOUT   (SEQT-1)          // 255 output steps
#define NBLK   256
#define THR    512
#define WLSTR  1032              // LDS weight k-stride (halves, padded)
#define ABUF   10240             // halves per A buffer plane (256*40)

typedef __attribute__((ext_vector_type(8))) short short8;
typedef __attribute__((ext_vector_type(4))) float f32x4;
typedef unsigned short u16;

__device__ __forceinline__ float sigm(float x)     { return 1.f / (1.f + __expf(-x)); }
__device__ __forceinline__ float tanhfast(float x) { return 1.f - 2.f / (1.f + __expf(2.f * x)); }

// round-to-nearest-even fp32 -> bf16 bits
__device__ __forceinline__ u16 bf16rn(float f) {
    union { float f; unsigned u; } v; v.f = f;
    unsigned r = v.u + 0x7fffu + ((v.u >> 16) & 1u);
    return (u16)(r >> 16);
}
__device__ __forceinline__ float bf2f(u16 h) {
    union { float f; unsigned u; } v; v.u = ((unsigned)h) << 16; return v.f;
}

// ---------------------------------------------------------------------------
// Zero h1 parity-1 hi/lo planes (h1(-1) = 0). ws is poisoned, never restored.
// ---------------------------------------------------------------------------
__global__ void k_zero(u16* __restrict__ h1h, u16* __restrict__ h1l)
{
    int i = blockIdx.x * 256 + threadIdx.x;
    if (i < BH) { h1h[BH + i] = 0; h1l[BH + i] = 0; }
}

// ---------------------------------------------------------------------------
// Fused per-(n,h) attention (round-2/3 verified math); output written T-major
// directly as split bf16 hi/lo planes: attnH/attnL[t][n][f].
// ---------------------------------------------------------------------------
__global__ __launch_bounds__(256) void k_attn(
    const float* __restrict__ x,  const float* __restrict__ wq,
    const float* __restrict__ wk, const float* __restrict__ wv,
    u16* __restrict__ attnH, u16* __restrict__ attnL)
{
    __shared__ float Ks[128][40];
    __shared__ float Vs[128][40];

    const int nb  = blockIdx.x;
    const int n   = nb >> 3, h = nb & 7;
    const int tid = threadIdx.x;
    const float* xbase = x + ((size_t)n * SEQT) * FEATD + h * HD;

    float qv[HD];
    {
        float xr[HD];
        const float4* xp = (const float4*)(xbase + (size_t)tid * FEATD);
        #pragma unroll
        for (int q4 = 0; q4 < 8; ++q4) {
            float4 v = xp[q4];
            xr[q4*4+0] = v.x; xr[q4*4+1] = v.y; xr[q4*4+2] = v.z; xr[q4*4+3] = v.w;
        }
        #pragma unroll
        for (int d = 0; d < HD; ++d) {
            float s = 0.f;
            #pragma unroll
            for (int e = 0; e < HD; ++e) s += xr[e] * wq[d*HD + e];
            qv[d] = s * 0.0625f;
        }
    }

    float o[HD];
    #pragma unroll
    for (int d = 0; d < HD; ++d) o[d] = 0.f;
    float m = -1e30f, ssum = 0.f;

    for (int tile = 0; tile < 2; ++tile) {
        const int j0 = tile * 128;
        __syncthreads();
        {
            const int r = tid & 127;
            const float* W = (tid < 128) ? wk : wv;
            float xt[HD];
            const float4* xp = (const float4*)(xbase + (size_t)(j0 + r) * FEATD);
            #pragma unroll
            for (int q4 = 0; q4 < 8; ++q4) {
                float4 v = xp[q4];
                xt[q4*4+0] = v.x; xt[q4*4+1] = v.y; xt[q4*4+2] = v.z; xt[q4*4+3] = v.w;
            }
            float outr[HD];
            #pragma unroll
            for (int d = 0; d < HD; ++d) {
                float s = 0.f;
                #pragma unroll
                for (int e = 0; e < HD; ++e) s += xt[e] * W[d*HD + e];
                outr[d] = s;
            }
            float (*dst)[40] = (tid < 128) ? Ks : Vs;
            #pragma unroll
            for (int d = 0; d < HD; ++d) dst[r][d] = outr[d];
        }
        __syncthreads();

        for (int j = 0; j < 128; ++j) {
            float e = 0.f;
            #pragma unroll
            for (int dq = 0; dq < 8; ++dq) {
                float4 kq = *(const float4*)&Ks[j][dq*4];
                e += qv[dq*4+0]*kq.x + qv[dq*4+1]*kq.y
                   + qv[dq*4+2]*kq.z + qv[dq*4+3]*kq.w;
            }
            if (e > m) {
                float sc = __expf(m - e);
                ssum *= sc;
                #pragma unroll
                for (int d = 0; d < HD; ++d) o[d] *= sc;
                m = e;
            }
            float p = __expf(e - m);
            ssum += p;
            #pragma unroll
            for (int dq = 0; dq < 8; ++dq) {
                float4 vq = *(const float4*)&Vs[j][dq*4];
                o[dq*4+0] += p * vq.x; o[dq*4+1] += p * vq.y;
                o[dq*4+2] += p * vq.z; o[dq*4+3] += p * vq.w;
            }
        }
    }

    const float inv = 1.f / ssum;
    const size_t ob = ((size_t)tid * BATCH + n) * FEATD + h * HD;
    #pragma unroll
    for (int dq = 0; dq < 8; ++dq) {
        ushort4 vh, vl;
        float v0 = o[dq*4+0]*inv, v1 = o[dq*4+1]*inv,
              v2 = o[dq*4+2]*inv, v3 = o[dq*4+3]*inv;
        u16 a = bf16rn(v0); vh.x = a; vl.x = bf16rn(v0 - bf2f(a));
        u16 b = bf16rn(v1); vh.y = b; vl.y = bf16rn(v1 - bf2f(b));
        u16 c = bf16rn(v2); vh.z = c; vl.z = bf16rn(v2 - bf2f(c));
        u16 d = bf16rn(v3); vh.w = d; vl.w = bf16rn(v3 - bf2f(d));
        *(ushort4*)(attnH + ob + dq*4) = vh;
        *(ushort4*)(attnL + ob + dq*4) = vl;
    }
}

// ---------------------------------------------------------------------------
// Wc = w_hid @ w_fc [512,256]; bc = w_hid @ b_fc + b_hid  (verified)
// ---------------------------------------------------------------------------
__global__ __launch_bounds__(256) void k_wcomb(
    const float* __restrict__ w_fc,  const float* __restrict__ b_fc,
    const float* __restrict__ w_hid, const float* __restrict__ b_hid,
    float* __restrict__ Wc, float* __restrict__ bc)
{
    const int i = blockIdx.x, j = threadIdx.x;
    float s = 0.f;
    for (int k = 0; k < FEATD; ++k) s += w_hid[i*FEATD + k] * w_fc[k*FEATD + j];
    Wc[(size_t)i*FEATD + j] = s;
    if (j == 0) {
        float t = b_hid[i];
        for (int k = 0; k < FEATD; ++k) t += w_hid[i*FEATD + k] * b_fc[k];
        bc[i] = t;
    }
}

// ---------------------------------------------------------------------------
// Wx0 = W_ih[0] @ Wc [2048,256]; bx0 = W_ih[0] @ bc + b_ih[0] + b_hh[0]
// ---------------------------------------------------------------------------
__global__ __launch_bounds__(256) void k_wx0(
    const float* __restrict__ w_ih, const float* __restrict__ Wc,
    const float* __restrict__ bc,   const float* __restrict__ b_ih,
    const float* __restrict__ b_hh,
    float* __restrict__ Wx0, float* __restrict__ bx0)
{
    const int i = blockIdx.x, j = threadIdx.x;
    float s = 0.f;
    for (int k = 0; k < HID; ++k) s += w_ih[(size_t)i*HID + k] * Wc[(size_t)k*FEATD + j];
    Wx0[(size_t)i*FEATD + j] = s;
    if (j == 0) {
        float t = b_ih[i] + b_hh[i];
        for (int k = 0; k < HID; ++k) t += w_ih[(size_t)i*HID + k] * bc[k];
        bx0[i] = t;
    }
}

// ---------------------------------------------------------------------------
// Device-scope grid barrier (round-3 verified mechanism).
// ---------------------------------------------------------------------------
__device__ __forceinline__ void grid_bar(int* bar, int target)
{
    __syncthreads();
    if (threadIdx.x == 0) {
        __threadfence();
        __hip_atomic_fetch_add(bar, 1, __ATOMIC_RELEASE, __HIP_MEMORY_SCOPE_AGENT);
        while (__hip_atomic_load(bar, __ATOMIC_RELAXED, __HIP_MEMORY_SCOPE_AGENT) < target)
            __builtin_amdgcn_s_sleep(2);
        __threadfence();
    }
    __syncthreads();
}

// ---------------------------------------------------------------------------
// Persistent MFMA LSTM. 256 blocks x 512 threads (8 waves, 2/SIMD).
// Blocks [0,128): layer1 (K=1024 = h0(t)|h1(t-1)); [128,256): layer0
// (K=768 = attn(t+1)|h0(t)). Block owns 16 gate-cols (4 h-cols), weights
// split-bf16 LDS-resident k-major. A-tiles [256x32] hi/lo double-buffered.
// Split-fp32 arithmetic: a*w ~= ah*wh + al*wh + ah*wl (3 MFMAs, err ~2^-18).
// c-state resident in LDS. h stored as global bf16 hi/lo planes.
// Projection relu(h1(t-1))@w_out^T done by layer-0 blocks (rows 2b,2b+1).
// ---------------------------------------------------------------------------
__global__ __launch_bounds__(THR, 2) void k_lstm(
    const u16* __restrict__ attnH, const u16* __restrict__ attnL,
    const float* __restrict__ Wx0, const float* __restrict__ bx0,
    u16* __restrict__ h0h, u16* __restrict__ h0l,
    u16* __restrict__ h1h, u16* __restrict__ h1l,
    const float* __restrict__ w_ih, const float* __restrict__ w_hh,
    const float* __restrict__ b_ih, const float* __restrict__ b_hh,
    const float* __restrict__ w_out, const float* __restrict__ b_out,
    float* __restrict__ out, int* __restrict__ bar)
{
    extern __shared__ char smem[];
    u16*   wlh  = (u16*)smem;                 // [16][WLSTR] hi plane
    u16*   wll  = wlh + 16*WLSTR;             // [16][WLSTR] lo plane
    u16*   Ah   = wll + 16*WLSTR;             // [2][256][40] hi tiles
    u16*   Al   = Ah + 2*ABUF;                // [2][256][40] lo tiles
    float* cres = (float*)(Al + 2*ABUF);      // [256][4] cell state
    float* bias = cres + 256*4;               // [16]
    float* Cb   = (float*)Ah;                 // epilogue bounce (alias)

    const int tid = threadIdx.x;
    const bool lay1 = (blockIdx.x < 128);
    const int b   = lay1 ? blockIdx.x : blockIdx.x - 128;
    const int hc0 = b * 4;
    const int wid = tid >> 6, l = tid & 63;

    // ---- stage weights once: split fp32 -> bf16 hi/lo, k-major per col
    {
        const int KW = lay1 ? 1024 : 768;
        for (int c = 0; c < 16; ++c) {
            const int g = c & 3, dc = c >> 2;
            const int grow = g*HID + hc0 + dc;
            const float* src0; const float* src1; int klen0;
            if (lay1) {
                src0 = w_ih + (size_t)GATES*HID + (size_t)grow*HID; klen0 = 512;
                src1 = w_hh + (size_t)GATES*HID + (size_t)grow*HID;
            } else {
                src0 = Wx0 + (size_t)grow*FEATD;                    klen0 = 256;
                src1 = w_hh + (size_t)grow*HID;
            }
            for (int k = tid; k < KW; k += THR) {
                float f = (k < klen0) ? src0[k] : src1[k - klen0];
                u16 hi = bf16rn(f);
                wlh[c*WLSTR + k] = hi;
                wll[c*WLSTR + k] = bf16rn(f - bf2f(hi));
            }
        }
    }
    if (tid < 16) {
        const int g = tid & 3, dc = tid >> 2, grow = g*HID + hc0 + dc;
        bias[tid] = lay1 ? (b_ih[GATES + grow] + b_hh[GATES + grow]) : bx0[grow];
    }
    for (int i = tid; i < 256*4; i += THR) cres[i] = 0.f;
    __syncthreads();

    // ---- staging helpers (reg-prefetch then LDS write)
    uint4 regs[4];
    auto stage_load = [&](const u16* sH, const u16* sL, int stride, int k0) {
        #pragma unroll
        for (int i = 0; i < 2; ++i) {
            const int id = tid + THR*i, row = id >> 2, kg = id & 3;
            regs[i]   = *(const uint4*)(sH + (size_t)row*stride + k0 + kg*8);
            regs[2+i] = *(const uint4*)(sL + (size_t)row*stride + k0 + kg*8);
        }
    };
    auto stage_write = [&](int buf) {
        #pragma unroll
        for (int i = 0; i < 2; ++i) {
            const int id = tid + THR*i, row = id >> 2, kg = id & 3;
            *(uint4*)(Ah + buf*ABUF + row*40 + kg*8) = regs[i];
            *(uint4*)(Al + buf*ABUF + row*40 + kg*8) = regs[2+i];
        }
    };

    // ---- one LSTM half-step: NT = nt0+nt1 K-slices of 32
    auto do_step = [&](const u16* s0H, const u16* s0L, int st0, int nt0,
                       const u16* s1H, const u16* s1L, int st1, int nt1,
                       u16* dH, u16* dL) {
        const int NT = nt0 + nt1;
        f32x4 acc0 = {0.f,0.f,0.f,0.f}, acc1 = {0.f,0.f,0.f,0.f};

        stage_load(s0H, s0L, st0, 0);
        stage_write(0);
        __syncthreads();

        const int arow = wid*32 + (l & 15);
        const int achk = (l >> 4) * 8;
        const int boff = (l & 15)*WLSTR + achk;

        for (int s = 0; s < NT; ++s) {
            const int buf = s & 1;
            if (s + 1 < NT) {
                const int s2 = s + 1;
                if (s2 < nt0) stage_load(s0H, s0L, st0, s2*32);
                else          stage_load(s1H, s1L, st1, (s2 - nt0)*32);
            }
            const u16* ah = Ah + buf*ABUF;
            const u16* al = Al + buf*ABUF;
            const short8 a_h0 = *(const short8*)(ah + arow*40 + achk);
            const short8 a_h1 = *(const short8*)(ah + (arow+16)*40 + achk);
            const short8 a_l0 = *(const short8*)(al + arow*40 + achk);
            const short8 a_l1 = *(const short8*)(al + (arow+16)*40 + achk);
            const short8 b_h  = *(const short8*)(wlh + boff + s*32);
            const short8 b_l  = *(const short8*)(wll + boff + s*32);
            acc0 = __builtin_amdgcn_mfma_f32_16x16x32_bf16(a_h0, b_h, acc0, 0,0,0);
            acc1 = __builtin_amdgcn_mfma_f32_16x16x32_bf16(a_h1, b_h, acc1, 0,0,0);
            acc0 = __builtin_amdgcn_mfma_f32_16x16x32_bf16(a_l0, b_h, acc0, 0,0,0);
            acc1 = __builtin_amdgcn_mfma_f32_16x16x32_bf16(a_l1, b_h, acc1, 0,0,0);
            acc0 = __builtin_amdgcn_mfma_f32_16x16x32_bf16(a_h0, b_l, acc0, 0,0,0);
            acc1 = __builtin_amdgcn_mfma_f32_16x16x32_bf16(a_h1, b_l, acc1, 0,0,0);
            if (s + 1 < NT) stage_write(buf ^ 1);
            __syncthreads();
        }

        // C fragments -> LDS bounce (row = batch, col = local gate-col)
        {
            const int crow = wid*32 + (l >> 4)*4;
            #pragma unroll
            for (int r = 0; r < 4; ++r) Cb[(crow + r)*16 + (l & 15)]      = acc0[r];
            #pragma unroll
            for (int r = 0; r < 4; ++r) Cb[(crow + 16 + r)*16 + (l & 15)] = acc1[r];
        }
        __syncthreads();

        if (tid < 256) {
            const int row = tid;
            ushort4 vh, vl;
            u16 hh[4], hl[4];
            #pragma unroll
            for (int dc = 0; dc < 4; ++dc) {
                const f32x4 gq = *(const f32x4*)&Cb[row*16 + dc*4];
                const float gi = sigm(gq[0] + bias[dc*4+0]);
                const float gf = sigm(gq[1] + bias[dc*4+1]);
                const float gg = tanhfast(gq[2] + bias[dc*4+2]);
                const float go = sigm(gq[3] + bias[dc*4+3]);
                const float cn = gf * cres[row*4 + dc] + gi * gg;
                cres[row*4 + dc] = cn;
                const float h = go * tanhfast(cn);
                hh[dc] = bf16rn(h);
                hl[dc] = bf16rn(h - bf2f(hh[dc]));
            }
            vh.x = hh[0]; vh.y = hh[1]; vh.z = hh[2]; vh.w = hh[3];
            vl.x = hl[0]; vl.y = hl[1]; vl.z = hl[2]; vl.w = hl[3];
            *(ushort4*)(dH + (size_t)row*HID + hc0) = vh;
            *(ushort4*)(dL + (size_t)row*HID + hc0) = vl;
        }
        __syncthreads();
    };

    // ---- projection: ypred[n=2b+r, tout, :] from global h1 hi/lo planes
    auto proj = [&](const u16* hH, const u16* hL, int tout) {
        if (tid < 256) {
            const int r  = tid >> 7;
            const int j  = (tid >> 4) & 7;
            const int ks = tid & 15;
            const int n  = 2*b + r;
            const size_t base = (size_t)n*HID + ks*32;
            float s = 0.f;
            #pragma unroll
            for (int k = 0; k < 32; ++k) {
                float hv = bf2f(hH[base + k]) + bf2f(hL[base + k]);
                hv = hv > 0.f ? hv : 0.f;
                s += hv * w_out[(size_t)j*HID + ks*32 + k];
            }
            s += __shfl_xor(s, 1);  s += __shfl_xor(s, 2);
            s += __shfl_xor(s, 4);  s += __shfl_xor(s, 8);
            if (ks == 0)
                out[(size_t)n*(TOUT*NHEADS) + (size_t)tout*NHEADS + j] = s + b_out[j];
        }
    };

    // ---- prologue: layer0 computes h0(0) from attn(0) (no recurrent input)
    if (!lay1)
        do_step(attnH, attnL, FEATD, 8, (const u16*)0, (const u16*)0, 0, 0,
                h0h, h0l);
    grid_bar(bar, 1*NBLK);

    // ---- pipelined: layer1(t) || layer0(t+1), t = 0..254
    for (int t = 0; t <= SEQT - 2; ++t) {
        if (lay1) {
            const int p = t & 1, q = p ^ 1;
            do_step(h0h + (size_t)p*BH, h0l + (size_t)p*BH, HID, 16,
                    h1h + (size_t)q*BH, h1l + (size_t)q*BH, HID, 16,
                    h1h + (size_t)p*BH, h1l + (size_t)p*BH);
        } else {
            if (t >= 1) {
                const int q = (t - 1) & 1;
                proj(h1h + (size_t)q*BH, h1l + (size_t)q*BH, t - 1);
            }
            if (t <= SEQT - 3) {
                const int tt = t + 1, p = t & 1, d = tt & 1;
                do_step(attnH + (size_t)tt*BATCH*FEATD, attnL + (size_t)tt*BATCH*FEATD,
                        FEATD, 8,
                        h0h + (size_t)p*BH, h0l + (size_t)p*BH, HID, 16,
                        h0h + (size_t)d*BH, h0l + (size_t)d*BH);
            }
        }
        grid_bar(bar, (t + 2)*NBLK);
    }

    // ---- tail: project h1(254) (parity 0)
    if (!lay1) proj(h1h, h1l, TOUT - 1);
}

// ---------------------------------------------------------------------------
extern "C" void kernel_launch(void* const* d_in, const int* in_sizes, int n_in,
                              void* d_out, int out_size, void* d_ws, size_t ws_size,
                              hipStream_t stream)
{
    (void)in_sizes; (void)n_in; (void)out_size; (void)ws_size;
    const float* x     = (const float*)d_in[0];
    const float* wq    = (const float*)d_in[1];
    const float* wk    = (const float*)d_in[2];
    const float* wv    = (const float*)d_in[3];
    const float* w_fc  = (const float*)d_in[4];
    const float* b_fc  = (const float*)d_in[5];
    const float* w_hid = (const float*)d_in[6];
    const float* b_hid = (const float*)d_in[7];
    const float* w_ih  = (const float*)d_in[8];
    const float* w_hh  = (const float*)d_in[9];
    const float* b_ih  = (const float*)d_in[10];
    const float* b_hh  = (const float*)d_in[11];
    const float* w_out = (const float*)d_in[12];
    const float* b_out = (const float*)d_in[13];

    float* ws = (float*)d_ws;
    size_t off = 0;
    u16* attnH = (u16*)(ws + off); off += (size_t)SEQT*BATCH*FEATD/2;  // 8.39M f
    u16* attnL = (u16*)(ws + off); off += (size_t)SEQT*BATCH*FEATD/2;
    float* Wc  = ws + off; off += (size_t)HID*FEATD;
    float* bc  = ws + off; off += HID;
    float* Wx0 = ws + off; off += (size_t)GATES*FEATD;
    float* bx0 = ws + off; off += GATES;
    u16* h0h = (u16*)(ws + off); off += BH;    // 2 parity slabs of ushort
    u16* h0l = (u16*)(ws + off); off += BH;
    u16* h1h = (u16*)(ws + off); off += BH;
    u16* h1l = (u16*)(ws + off); off += BH;
    int* bar = (int*)(ws + off); off += 64;
    // total ~18.0M floats = ~72 MB

    hipMemsetAsync(bar, 0, sizeof(int), stream);

    k_zero  <<<dim3(512),          dim3(256), 0, stream>>>(h1h, h1l);
    k_attn  <<<dim3(BATCH*NHEADS), dim3(256), 0, stream>>>(x, wq, wk, wv, attnH, attnL);
    k_wcomb <<<dim3(HID),          dim3(256), 0, stream>>>(w_fc, b_fc, w_hid, b_hid, Wc, bc);
    k_wx0   <<<dim3(GATES),        dim3(256), 0, stream>>>(w_ih, Wc, bc, b_ih, b_hh, Wx0, bx0);

    const int shmem = (16*WLSTR*2 + 2*ABUF*2)*2 + 256*4*4 + 16*4;  // 152128 B
    (void)hipFuncSetAttribute(reinterpret_cast<const void*>(k_lstm),
                              hipFuncAttributeMaxDynamicSharedMemorySize, shmem);
    k_lstm <<<dim3(NBLK), dim3(THR), (size_t)shmem, stream>>>(
        attnH, attnL, Wx0, bx0, h0h, h0l, h1h, h1l,
        w_ih, w_hh, b_ih, b_hh, w_out, b_out, (float*)d_out, bar);
}

// Round 5
// 14150.125 us; speedup vs baseline: 4.4685x; 1.6429x over previous
//
#include <hip/hip_runtime.h>
#include <math.h>

// Problem constants
#define BATCH  256
#define SEQT   256
#define FEATD  256
#define NHEADS 8
#define HD     32
#define HID    512
#define GATES  2048
#define BH     (BATCH*HID)       // halves per h plane (2 parity slabs of BH/... see alloc)
#define TOUT   (SEQT-1)
#define NBLK   256
#define THR    1024

typedef __attribute__((ext_vector_type(8))) short short8;
typedef __attribute__((ext_vector_type(4))) float f32x4;
typedef unsigned short u16;

__device__ __forceinline__ float sigm(float x)     { return 1.f / (1.f + __expf(-x)); }
__device__ __forceinline__ float tanhfast(float x) { return 1.f - 2.f / (1.f + __expf(2.f * x)); }

__device__ __forceinline__ u16 bf16rn(float f) {
    union { float f; unsigned u; } v; v.f = f;
    unsigned r = v.u + 0x7fffu + ((v.u >> 16) & 1u);
    return (u16)(r >> 16);
}
__device__ __forceinline__ float bf2f(u16 h) {
    union { float f; unsigned u; } v; v.u = ((unsigned)h) << 16; return v.f;
}

// ---------------------------------------------------------------------------
// Fused per-(n,h) attention (verified math). Output T-major in COL-BLOCK
// layout: attn[t][cb=f/4][n][4] split bf16 hi/lo planes (65536 halves per t).
// ---------------------------------------------------------------------------
__global__ __launch_bounds__(256) void k_attn(
    const float* __restrict__ x,  const float* __restrict__ wq,
    const float* __restrict__ wk, const float* __restrict__ wv,
    u16* __restrict__ attnH, u16* __restrict__ attnL)
{
    __shared__ float Ks[128][40];
    __shared__ float Vs[128][40];

    const int nb  = blockIdx.x;
    const int n   = nb >> 3, h = nb & 7;
    const int tid = threadIdx.x;
    const float* xbase = x + ((size_t)n * SEQT) * FEATD + h * HD;

    float qv[HD];
    {
        float xr[HD];
        const float4* xp = (const float4*)(xbase + (size_t)tid * FEATD);
        #pragma unroll
        for (int q4 = 0; q4 < 8; ++q4) {
            float4 v = xp[q4];
            xr[q4*4+0] = v.x; xr[q4*4+1] = v.y; xr[q4*4+2] = v.z; xr[q4*4+3] = v.w;
        }
        #pragma unroll
        for (int d = 0; d < HD; ++d) {
            float s = 0.f;
            #pragma unroll
            for (int e = 0; e < HD; ++e) s += xr[e] * wq[d*HD + e];
            qv[d] = s * 0.0625f;
        }
    }

    float o[HD];
    #pragma unroll
    for (int d = 0; d < HD; ++d) o[d] = 0.f;
    float m = -1e30f, ssum = 0.f;

    for (int tile = 0; tile < 2; ++tile) {
        const int j0 = tile * 128;
        __syncthreads();
        {
            const int r = tid & 127;
            const float* W = (tid < 128) ? wk : wv;
            float xt[HD];
            const float4* xp = (const float4*)(xbase + (size_t)(j0 + r) * FEATD);
            #pragma unroll
            for (int q4 = 0; q4 < 8; ++q4) {
                float4 v = xp[q4];
                xt[q4*4+0] = v.x; xt[q4*4+1] = v.y; xt[q4*4+2] = v.z; xt[q4*4+3] = v.w;
            }
            float outr[HD];
            #pragma unroll
            for (int d = 0; d < HD; ++d) {
                float s = 0.f;
                #pragma unroll
                for (int e = 0; e < HD; ++e) s += xt[e] * W[d*HD + e];
                outr[d] = s;
            }
            float (*dst)[40] = (tid < 128) ? Ks : Vs;
            #pragma unroll
            for (int d = 0; d < HD; ++d) dst[r][d] = outr[d];
        }
        __syncthreads();

        for (int j = 0; j < 128; ++j) {
            float e = 0.f;
            #pragma unroll
            for (int dq = 0; dq < 8; ++dq) {
                float4 kq = *(const float4*)&Ks[j][dq*4];
                e += qv[dq*4+0]*kq.x + qv[dq*4+1]*kq.y
                   + qv[dq*4+2]*kq.z + qv[dq*4+3]*kq.w;
            }
            if (e > m) {
                float sc = __expf(m - e);
                ssum *= sc;
                #pragma unroll
                for (int d = 0; d < HD; ++d) o[d] *= sc;
                m = e;
            }
            float p = __expf(e - m);
            ssum += p;
            #pragma unroll
            for (int dq = 0; dq < 8; ++dq) {
                float4 vq = *(const float4*)&Vs[j][dq*4];
                o[dq*4+0] += p * vq.x; o[dq*4+1] += p * vq.y;
                o[dq*4+2] += p * vq.z; o[dq*4+3] += p * vq.w;
            }
        }
    }

    const float inv = 1.f / ssum;
    const size_t tb = (size_t)tid * 65536 + (size_t)n * 4;   // t-slice, row n
    #pragma unroll
    for (int dq = 0; dq < 8; ++dq) {
        ushort4 vh, vl;
        float v0 = o[dq*4+0]*inv, v1 = o[dq*4+1]*inv,
              v2 = o[dq*4+2]*inv, v3 = o[dq*4+3]*inv;
        u16 a0 = bf16rn(v0); vh.x = a0; vl.x = bf16rn(v0 - bf2f(a0));
        u16 a1 = bf16rn(v1); vh.y = a1; vl.y = bf16rn(v1 - bf2f(a1));
        u16 a2 = bf16rn(v2); vh.z = a2; vl.z = bf16rn(v2 - bf2f(a2));
        u16 a3 = bf16rn(v3); vh.w = a3; vl.w = bf16rn(v3 - bf2f(a3));
        const size_t a = tb + (size_t)(h*8 + dq) * 1024;     // cb = h*8+dq
        *(ushort4*)(attnH + a) = vh;
        *(ushort4*)(attnL + a) = vl;
    }
}

// ---------------------------------------------------------------------------
// Wc = w_hid @ w_fc [512,256]; bc = w_hid @ b_fc + b_hid  (verified)
// ---------------------------------------------------------------------------
__global__ __launch_bounds__(256) void k_wcomb(
    const float* __restrict__ w_fc,  const float* __restrict__ b_fc,
    const float* __restrict__ w_hid, const float* __restrict__ b_hid,
    float* __restrict__ Wc, float* __restrict__ bc)
{
    const int i = blockIdx.x, j = threadIdx.x;
    float s = 0.f;
    for (int k = 0; k < FEATD; ++k) s += w_hid[i*FEATD + k] * w_fc[k*FEATD + j];
    Wc[(size_t)i*FEATD + j] = s;
    if (j == 0) {
        float t = b_hid[i];
        for (int k = 0; k < FEATD; ++k) t += w_hid[i*FEATD + k] * b_fc[k];
        bc[i] = t;
    }
}

// ---------------------------------------------------------------------------
// Wx0 = W_ih[0] @ Wc [2048,256]; bx0 = W_ih[0] @ bc + b_ih[0] + b_hh[0]
// ---------------------------------------------------------------------------
__global__ __launch_bounds__(256) void k_wx0(
    const float* __restrict__ w_ih, const float* __restrict__ Wc,
    const float* __restrict__ bc,   const float* __restrict__ b_ih,
    const float* __restrict__ b_hh,
    float* __restrict__ Wx0, float* __restrict__ bx0)
{
    const int i = blockIdx.x, j = threadIdx.x;
    float s = 0.f;
    for (int k = 0; k < HID; ++k) s += w_ih[(size_t)i*HID + k] * Wc[(size_t)k*FEATD + j];
    Wx0[(size_t)i*FEATD + j] = s;
    if (j == 0) {
        float t = b_ih[i] + b_hh[i];
        for (int k = 0; k < HID; ++k) t += w_ih[(size_t)i*HID + k] * bc[k];
        bx0[i] = t;
    }
}

// ---------------------------------------------------------------------------
// Device-scope grid barrier (verified mechanism, rounds 3-4).
// ---------------------------------------------------------------------------
__device__ __forceinline__ void grid_bar(int* bar, int target)
{
    __syncthreads();
    if (threadIdx.x == 0) {
        __threadfence();
        __hip_atomic_fetch_add(bar, 1, __ATOMIC_RELEASE, __HIP_MEMORY_SCOPE_AGENT);
        while (__hip_atomic_load(bar, __ATOMIC_RELAXED, __HIP_MEMORY_SCOPE_AGENT) < target)
            __builtin_amdgcn_s_sleep(2);
        __threadfence();
    }
    __syncthreads();
}

// ---------------------------------------------------------------------------
// Persistent MFMA LSTM. 256 blocks x 1024 threads (16 waves, 4/SIMD).
// Layer L in {1:blocks 0..127, 0:blocks 128..255}; block = (cg 0..63, mg 0..1):
// owns 32 gate-cols (8 h-cols, hc = cg*8..+7) x 128 batch rows (mg*128..).
// Weights split-bf16 LDS-resident [32 cols][KSTR k-major]. A operand read
// DIRECTLY from global col-block layout [cb][256 rows][4] into MFMA frags
// (no LDS staging, no per-slice barriers, depth-2 reg prefetch).
// 16 waves = 8 M-tiles x 2 N-tiles of 16x16x32 bf16 MFMA, 3-term split-fp32.
// c-state in one register/thread. 2 __syncthreads per step + 1 grid barrier.
// ---------------------------------------------------------------------------
__global__ __launch_bounds__(THR, 1) void k_lstm(
    const u16* __restrict__ attnH, const u16* __restrict__ attnL,
    const float* __restrict__ Wx0, const float* __restrict__ bx0,
    u16* __restrict__ h0h, u16* __restrict__ h0l,
    u16* __restrict__ h1h, u16* __restrict__ h1l,
    const float* __restrict__ w_ih, const float* __restrict__ w_hh,
    const float* __restrict__ b_ih, const float* __restrict__ b_hh,
    const float* __restrict__ w_out, const float* __restrict__ b_out,
    float* __restrict__ out, int* __restrict__ bar)
{
    extern __shared__ char smem[];
    const int tid  = threadIdx.x;
    const int bx   = blockIdx.x;
    const bool lay1 = (bx < 128);
    const int idx  = lay1 ? bx : bx - 128;
    const int cg   = idx >> 1;          // col-group 0..63
    const int mg   = idx & 1;           // row-group 0..1
    const int KSTR = lay1 ? 1032 : 776; // padded k-stride (halves), ==4 mod 32 words
    const int KW   = lay1 ? 1024 : 768;

    u16*   wlh = (u16*)smem;
    u16*   wll = wlh + 32*KSTR;
    float* Cb  = (float*)(smem + 132096);   // [128][33] gate bounce

    // wave/lane geometry
    const int wid = tid >> 6, l = tid & 63;
    const int Mtile = wid & 7, Ntile = wid >> 3;
    const int lr = l & 15, aq = l >> 4;
    const int rowg = mg*128 + Mtile*16 + lr;          // global batch row for A/C
    const int achk = aq * 8;                          // k-chunk within 32-slice
    const int col_local = Ntile*16 + lr;              // 0..31
    const int boff = col_local*KSTR + achk;

    // ---- stage weights once: split fp32 -> bf16 hi/lo, k-major per col
    for (int c = 0; c < 32; ++c) {
        const int grow = (c >> 3)*HID + cg*8 + (c & 7);
        const float* src0; const float* src1; int klen0;
        if (lay1) {
            src0 = w_ih + (size_t)GATES*HID + (size_t)grow*HID; klen0 = 512;
            src1 = w_hh + (size_t)GATES*HID + (size_t)grow*HID;
        } else {
            src0 = Wx0 + (size_t)grow*FEATD;                    klen0 = 256;
            src1 = w_hh + (size_t)grow*HID;
        }
        for (int k = tid; k < KW; k += THR) {
            float f = (k < klen0) ? src0[k] : src1[k - klen0];
            u16 hi = bf16rn(f);
            wlh[c*KSTR + k] = hi;
            wll[c*KSTR + k] = bf16rn(f - bf2f(hi));
        }
    }

    // ---- per-thread epilogue constants: thread -> (row=tid&127, hcl=tid>>7)
    const int erow = tid & 127, hcl = tid >> 7;
    float bsum[4];
    #pragma unroll
    for (int g = 0; g < 4; ++g) {
        const int gidx = g*HID + cg*8 + hcl;
        bsum[g] = lay1 ? (b_ih[GATES + gidx] + b_hh[GATES + gidx]) : bx0[gidx];
    }
    float cr = 0.f;                       // cell state (register-resident)
    __syncthreads();

    union U8 { uint2 u2[2]; short8 s8; };

    // one LSTM step for this block: A = [src0 (nt0 slices) | src1], NT total
    auto do_step = [&](const u16* s0H, const u16* s0L, int nt0,
                       const u16* s1H, const u16* s1L, int NT,
                       u16* dH, u16* dL) {
        f32x4 acc = {0.f, 0.f, 0.f, 0.f};
        uint2 sA[4], sB[4];

        auto loadA = [&](uint2* st, int s) {
            const u16 *pH, *pL; int c0;
            if (s < nt0) { pH = s0H; pL = s0L; c0 = s*32; }
            else         { pH = s1H; pL = s1L; c0 = (s - nt0)*32; }
            const size_t a0 = ((size_t)(c0 >> 2) + (size_t)(aq << 1))*1024
                            + (size_t)rowg*4;
            st[0] = *(const uint2*)(pH + a0);
            st[1] = *(const uint2*)(pH + a0 + 1024);
            st[2] = *(const uint2*)(pL + a0);
            st[3] = *(const uint2*)(pL + a0 + 1024);
        };

        loadA(sA, 0);
        loadA(sB, 1);                     // NT >= 8 always

        for (int s = 0; s < NT; s += 2) { // NT always even
            {   // even slice from sA
                U8 ua, ul;
                ua.u2[0] = sA[0]; ua.u2[1] = sA[1];
                ul.u2[0] = sA[2]; ul.u2[1] = sA[3];
                if (s + 2 < NT) loadA(sA, s + 2);
                const short8 bh = *(const short8*)(wlh + boff + s*32);
                const short8 bl = *(const short8*)(wll + boff + s*32);
                acc = __builtin_amdgcn_mfma_f32_16x16x32_bf16(ua.s8, bh, acc, 0,0,0);
                acc = __builtin_amdgcn_mfma_f32_16x16x32_bf16(ul.s8, bh, acc, 0,0,0);
                acc = __builtin_amdgcn_mfma_f32_16x16x32_bf16(ua.s8, bl, acc, 0,0,0);
            }
            {   // odd slice from sB
                U8 ua, ul;
                ua.u2[0] = sB[0]; ua.u2[1] = sB[1];
                ul.u2[0] = sB[2]; ul.u2[1] = sB[3];
                if (s + 3 < NT) loadA(sB, s + 3);
                const short8 bh = *(const short8*)(wlh + boff + (s+1)*32);
                const short8 bl = *(const short8*)(wll + boff + (s+1)*32);
                acc = __builtin_amdgcn_mfma_f32_16x16x32_bf16(ua.s8, bh, acc, 0,0,0);
                acc = __builtin_amdgcn_mfma_f32_16x16x32_bf16(ul.s8, bh, acc, 0,0,0);
                acc = __builtin_amdgcn_mfma_f32_16x16x32_bf16(ua.s8, bl, acc, 0,0,0);
            }
        }

        // C fragments -> LDS bounce: Cb[row_local][col_local], stride 33
        {
            const int crow = Mtile*16 + aq*4;
            #pragma unroll
            for (int r = 0; r < 4; ++r)
                Cb[(crow + r)*33 + col_local] = acc[r];
        }
        __syncthreads();

        // gates: thread -> (erow, hcl); cols {g*8+hcl}
        {
            float g4[4];
            #pragma unroll
            for (int g = 0; g < 4; ++g) g4[g] = Cb[erow*33 + g*8 + hcl] + bsum[g];
            const float gi = sigm(g4[0]), gf = sigm(g4[1]);
            const float gg = tanhfast(g4[2]), go = sigm(g4[3]);
            cr = gf*cr + gi*gg;
            const float h = go * tanhfast(cr);
            const u16 hh = bf16rn(h);
            const u16 hl = bf16rn(h - bf2f(hh));
            const size_t a = (size_t)(cg*2 + (hcl >> 2))*1024
                           + (size_t)(mg*128 + erow)*4 + (hcl & 3);
            dH[a] = hh; dL[a] = hl;
        }
    };

    // projection: rows 2*idx, 2*idx+1 (layer-0 blocks only)
    auto proj = [&](const u16* hH, const u16* hL, int tout) {
        if (tid < 256) {
            const int r = tid >> 7, j = (tid >> 4) & 7, ks = tid & 15;
            const int n = 2*idx + r;
            float s = 0.f;
            #pragma unroll
            for (int kk = 0; kk < 32; ++kk) {
                const int k = ks*32 + kk;
                const size_t a = (size_t)(k >> 2)*1024 + (size_t)n*4 + (k & 3);
                float hv = bf2f(hH[a]) + bf2f(hL[a]);
                hv = hv > 0.f ? hv : 0.f;
                s += hv * w_out[(size_t)j*HID + k];
            }
            s += __shfl_xor(s, 1); s += __shfl_xor(s, 2);
            s += __shfl_xor(s, 4); s += __shfl_xor(s, 8);
            if (ks == 0)
                out[(size_t)n*(TOUT*NHEADS) + (size_t)tout*NHEADS + j] = s + b_out[j];
        }
    };

    // ---- prologue: layer0 computes h0(0) from attn(0) only
    if (!lay1)
        do_step(attnH, attnL, 8, (const u16*)0, (const u16*)0, 8, h0h, h0l);
    grid_bar(bar, 1*NBLK);

    // ---- pipelined: layer1(t) || layer0(t+1), t = 0..254
    for (int t = 0; t <= SEQT - 2; ++t) {
        if (lay1) {
            const int p = t & 1, q = p ^ 1;
            do_step(h0h + (size_t)p*BH, h0l + (size_t)p*BH, 16,
                    h1h + (size_t)q*BH, h1l + (size_t)q*BH,
                    (t == 0) ? 16 : 32,
                    h1h + (size_t)p*BH, h1l + (size_t)p*BH);
        } else {
            if (t >= 1) {
                const int q = (t - 1) & 1;
                proj(h1h + (size_t)q*BH, h1l + (size_t)q*BH, t - 1);
            }
            if (t <= SEQT - 3) {
                const int tt = t + 1, p = t & 1, d = tt & 1;
                do_step(attnH + (size_t)tt*65536, attnL + (size_t)tt*65536, 8,
                        h0h + (size_t)p*BH, h0l + (size_t)p*BH, 24,
                        h0h + (size_t)d*BH, h0l + (size_t)d*BH);
            }
        }
        grid_bar(bar, (t + 2)*NBLK);
    }

    // ---- tail: project h1(254) (parity 0)
    if (!lay1) proj(h1h, h1l, TOUT - 1);
}

// ---------------------------------------------------------------------------
extern "C" void kernel_launch(void* const* d_in, const int* in_sizes, int n_in,
                              void* d_out, int out_size, void* d_ws, size_t ws_size,
                              hipStream_t stream)
{
    (void)in_sizes; (void)n_in; (void)out_size; (void)ws_size;
    const float* x     = (const float*)d_in[0];
    const float* wq    = (const float*)d_in[1];
    const float* wk    = (const float*)d_in[2];
    const float* wv    = (const float*)d_in[3];
    const float* w_fc  = (const float*)d_in[4];
    const float* b_fc  = (const float*)d_in[5];
    const float* w_hid = (const float*)d_in[6];
    const float* b_hid = (const float*)d_in[7];
    const float* w_ih  = (const float*)d_in[8];
    const float* w_hh  = (const float*)d_in[9];
    const float* b_ih  = (const float*)d_in[10];
    const float* b_hh  = (const float*)d_in[11];
    const float* w_out = (const float*)d_in[12];
    const float* b_out = (const float*)d_in[13];

    float* ws = (float*)d_ws;
    size_t off = 0;
    u16* attnH = (u16*)(ws + off); off += (size_t)SEQT*BATCH*FEATD/2;
    u16* attnL = (u16*)(ws + off); off += (size_t)SEQT*BATCH*FEATD/2;
    float* Wc  = ws + off; off += (size_t)HID*FEATD;
    float* bc  = ws + off; off += HID;
    float* Wx0 = ws + off; off += (size_t)GATES*FEATD;
    float* bx0 = ws + off; off += GATES;
    u16* h0h = (u16*)(ws + off); off += BH;    // 2 parity slabs (BH halves each)
    u16* h0l = (u16*)(ws + off); off += BH;
    u16* h1h = (u16*)(ws + off); off += BH;
    u16* h1l = (u16*)(ws + off); off += BH;
    int* bar = (int*)(ws + off); off += 64;

    hipMemsetAsync(bar, 0, sizeof(int), stream);

    k_attn  <<<dim3(BATCH*NHEADS), dim3(256), 0, stream>>>(x, wq, wk, wv, attnH, attnL);
    k_wcomb <<<dim3(HID),          dim3(256), 0, stream>>>(w_fc, b_fc, w_hid, b_hid, Wc, bc);
    k_wx0   <<<dim3(GATES),        dim3(256), 0, stream>>>(w_ih, Wc, bc, b_ih, b_hh, Wx0, bx0);

    const int shmem = 132096 + 128*33*4;   // weights (max, L1) + Cb = 148992 B
    (void)hipFuncSetAttribute(reinterpret_cast<const void*>(k_lstm),
                              hipFuncAttributeMaxDynamicSharedMemorySize, shmem);
    k_lstm <<<dim3(NBLK), dim3(THR), (size_t)shmem, stream>>>(
        attnH, attnL, Wx0, bx0, h0h, h0l, h1h, h1l,
        w_ih, w_hh, b_ih, b_hh, w_out, b_out, (float*)d_out, bar);
}

// Round 6
// 13088.414 us; speedup vs baseline: 4.8310x; 1.0811x over previous
//
#include <hip/hip_runtime.h>
#include <math.h>

// Problem constants
#define BATCH  256
#define SEQT   256
#define FEATD  256
#define NHEADS 8
#define HD     32
#define HID    512
#define GATES  2048
#define BH     (BATCH*HID)       // halves per h plane parity slab
#define TOUT   (SEQT-1)
#define NBLK   256
#define THR    1024
#define DEPTH  6                 // prefetch depth (slices)

typedef __attribute__((ext_vector_type(8))) short short8;
typedef __attribute__((ext_vector_type(4))) float f32x4;
typedef unsigned short u16;

union U8 { uint4 u4; short8 s8; };

__device__ __forceinline__ float sigm(float x)     { return 1.f / (1.f + __expf(-x)); }
__device__ __forceinline__ float tanhfast(float x) { return 1.f - 2.f / (1.f + __expf(2.f * x)); }

__device__ __forceinline__ u16 bf16rn(float f) {
    union { float f; unsigned u; } v; v.f = f;
    unsigned r = v.u + 0x7fffu + ((v.u >> 16) & 1u);
    return (u16)(r >> 16);
}
__device__ __forceinline__ float bf2f(u16 h) {
    union { float f; unsigned u; } v; v.u = ((unsigned)h) << 16; return v.f;
}

// ---------------------------------------------------------------------------
// Fused per-(n,h) attention (verified math). Output T-major in CB8 layout:
// attn[t][cb8=f/8][n][8] split bf16 hi/lo planes (65536 halves per t-slice).
// ---------------------------------------------------------------------------
__global__ __launch_bounds__(256) void k_attn(
    const float* __restrict__ x,  const float* __restrict__ wq,
    const float* __restrict__ wk, const float* __restrict__ wv,
    u16* __restrict__ attnH, u16* __restrict__ attnL)
{
    __shared__ float Ks[128][40];
    __shared__ float Vs[128][40];

    const int nb  = blockIdx.x;
    const int n   = nb >> 3, h = nb & 7;
    const int tid = threadIdx.x;
    const float* xbase = x + ((size_t)n * SEQT) * FEATD + h * HD;

    float qv[HD];
    {
        float xr[HD];
        const float4* xp = (const float4*)(xbase + (size_t)tid * FEATD);
        #pragma unroll
        for (int q4 = 0; q4 < 8; ++q4) {
            float4 v = xp[q4];
            xr[q4*4+0] = v.x; xr[q4*4+1] = v.y; xr[q4*4+2] = v.z; xr[q4*4+3] = v.w;
        }
        #pragma unroll
        for (int d = 0; d < HD; ++d) {
            float s = 0.f;
            #pragma unroll
            for (int e = 0; e < HD; ++e) s += xr[e] * wq[d*HD + e];
            qv[d] = s * 0.0625f;
        }
    }

    float o[HD];
    #pragma unroll
    for (int d = 0; d < HD; ++d) o[d] = 0.f;
    float m = -1e30f, ssum = 0.f;

    for (int tile = 0; tile < 2; ++tile) {
        const int j0 = tile * 128;
        __syncthreads();
        {
            const int r = tid & 127;
            const float* W = (tid < 128) ? wk : wv;
            float xt[HD];
            const float4* xp = (const float4*)(xbase + (size_t)(j0 + r) * FEATD);
            #pragma unroll
            for (int q4 = 0; q4 < 8; ++q4) {
                float4 v = xp[q4];
                xt[q4*4+0] = v.x; xt[q4*4+1] = v.y; xt[q4*4+2] = v.z; xt[q4*4+3] = v.w;
            }
            float outr[HD];
            #pragma unroll
            for (int d = 0; d < HD; ++d) {
                float s = 0.f;
                #pragma unroll
                for (int e = 0; e < HD; ++e) s += xt[e] * W[d*HD + e];
                outr[d] = s;
            }
            float (*dst)[40] = (tid < 128) ? Ks : Vs;
            #pragma unroll
            for (int d = 0; d < HD; ++d) dst[r][d] = outr[d];
        }
        __syncthreads();

        for (int j = 0; j < 128; ++j) {
            float e = 0.f;
            #pragma unroll
            for (int dq = 0; dq < 8; ++dq) {
                float4 kq = *(const float4*)&Ks[j][dq*4];
                e += qv[dq*4+0]*kq.x + qv[dq*4+1]*kq.y
                   + qv[dq*4+2]*kq.z + qv[dq*4+3]*kq.w;
            }
            if (e > m) {
                float sc = __expf(m - e);
                ssum *= sc;
                #pragma unroll
                for (int d = 0; d < HD; ++d) o[d] *= sc;
                m = e;
            }
            float p = __expf(e - m);
            ssum += p;
            #pragma unroll
            for (int dq = 0; dq < 8; ++dq) {
                float4 vq = *(const float4*)&Vs[j][dq*4];
                o[dq*4+0] += p * vq.x; o[dq*4+1] += p * vq.y;
                o[dq*4+2] += p * vq.z; o[dq*4+3] += p * vq.w;
            }
        }
    }

    const float inv = 1.f / ssum;
    #pragma unroll
    for (int dq = 0; dq < 8; ++dq) {
        ushort4 vh, vl;
        float v0 = o[dq*4+0]*inv, v1 = o[dq*4+1]*inv,
              v2 = o[dq*4+2]*inv, v3 = o[dq*4+3]*inv;
        u16 a0 = bf16rn(v0); vh.x = a0; vl.x = bf16rn(v0 - bf2f(a0));
        u16 a1 = bf16rn(v1); vh.y = a1; vl.y = bf16rn(v1 - bf2f(a1));
        u16 a2 = bf16rn(v2); vh.z = a2; vl.z = bf16rn(v2 - bf2f(a2));
        u16 a3 = bf16rn(v3); vh.w = a3; vl.w = bf16rn(v3 - bf2f(a3));
        // f = h*32 + dq*4 + c  ->  cb8 = h*4 + (dq>>1), off = (dq&1)*4 + c
        const size_t a = (size_t)tid*65536
                       + (size_t)(h*4 + (dq >> 1))*2048
                       + (size_t)n*8 + (dq & 1)*4;
        *(ushort4*)(attnH + a) = vh;
        *(ushort4*)(attnL + a) = vl;
    }
}

// ---------------------------------------------------------------------------
// Wc = w_hid @ w_fc [512,256]; bc = w_hid @ b_fc + b_hid  (verified)
// ---------------------------------------------------------------------------
__global__ __launch_bounds__(256) void k_wcomb(
    const float* __restrict__ w_fc,  const float* __restrict__ b_fc,
    const float* __restrict__ w_hid, const float* __restrict__ b_hid,
    float* __restrict__ Wc, float* __restrict__ bc)
{
    const int i = blockIdx.x, j = threadIdx.x;
    float s = 0.f;
    for (int k = 0; k < FEATD; ++k) s += w_hid[i*FEATD + k] * w_fc[k*FEATD + j];
    Wc[(size_t)i*FEATD + j] = s;
    if (j == 0) {
        float t = b_hid[i];
        for (int k = 0; k < FEATD; ++k) t += w_hid[i*FEATD + k] * b_fc[k];
        bc[i] = t;
    }
}

// ---------------------------------------------------------------------------
// Wx0 = W_ih[0] @ Wc [2048,256]; bx0 = W_ih[0] @ bc + b_ih[0] + b_hh[0]
// ---------------------------------------------------------------------------
__global__ __launch_bounds__(256) void k_wx0(
    const float* __restrict__ w_ih, const float* __restrict__ Wc,
    const float* __restrict__ bc,   const float* __restrict__ b_ih,
    const float* __restrict__ b_hh,
    float* __restrict__ Wx0, float* __restrict__ bx0)
{
    const int i = blockIdx.x, j = threadIdx.x;
    float s = 0.f;
    for (int k = 0; k < HID; ++k) s += w_ih[(size_t)i*HID + k] * Wc[(size_t)k*FEATD + j];
    Wx0[(size_t)i*FEATD + j] = s;
    if (j == 0) {
        float t = b_ih[i] + b_hh[i];
        for (int k = 0; k < HID; ++k) t += w_ih[(size_t)i*HID + k] * bc[k];
        bx0[i] = t;
    }
}

// ---------------------------------------------------------------------------
// Device-scope grid barrier (verified mechanism, rounds 3-5).
// ---------------------------------------------------------------------------
__device__ __forceinline__ void grid_bar(int* bar, int target)
{
    __syncthreads();
    if (threadIdx.x == 0) {
        __threadfence();
        __hip_atomic_fetch_add(bar, 1, __ATOMIC_RELEASE, __HIP_MEMORY_SCOPE_AGENT);
        while (__hip_atomic_load(bar, __ATOMIC_RELAXED, __HIP_MEMORY_SCOPE_AGENT) < target)
            __builtin_amdgcn_s_sleep(2);
        __threadfence();
    }
    __syncthreads();
}

// ---------------------------------------------------------------------------
// Per-block geometry for the LSTM step (all thread-invariant or per-thread
// scalars; passed by const ref so everything stays in registers).
// ---------------------------------------------------------------------------
struct Geo {
    const u16* wlh; const u16* wll;   // LDS weights (k-major per col)
    float* Cb;                        // LDS gate bounce [128][33]
    int rowg;                         // global batch row of A fragment
    int aq;                           // k-quarter (lane>>4)
    int boff;                         // B fragment base in wlh/wll
    int Mtile, col_local;             // C placement
    int erow, hcl;                    // epilogue row / h-col
    int cg, mg;                       // col-group, row-group
    const float* bsum;                // per-thread gate biases [4]
};

// One LSTM step for this block. A = [s0 (NT0 slices) | s1], NT slices total,
// each slice = K=32. CB8 source layout: elem (row, k) at (k>>3)*2048 + row*8
// + (k&7). Depth-DEPTH register prefetch of dwordx4 pairs (hi/lo planes).
template<int NT0, int NT>
__device__ __forceinline__ void do_step(
    const Geo& G,
    const u16* __restrict__ s0H, const u16* __restrict__ s0L,
    const u16* __restrict__ s1H, const u16* __restrict__ s1L,
    u16* __restrict__ dH, u16* __restrict__ dL, float& cr)
{
    uint4 pfH[DEPTH], pfL[DEPTH];

    auto loadA = [&](int d, int s) {
        const u16* pH = (s < NT0) ? s0H : s1H;
        const u16* pL = (s < NT0) ? s0L : s1L;
        const int sl  = (s < NT0) ? s : s - NT0;
        const size_t a = ((size_t)(sl*4 + G.aq) << 11) + (size_t)G.rowg * 8;
        pfH[d] = *(const uint4*)(pH + a);
        pfL[d] = *(const uint4*)(pL + a);
    };

    constexpr int PRIME = (DEPTH < NT) ? DEPTH : NT;
    #pragma unroll
    for (int d = 0; d < PRIME; ++d) loadA(d, d);

    f32x4 acc = {0.f, 0.f, 0.f, 0.f};
    #pragma unroll
    for (int s = 0; s < NT; ++s) {
        U8 ua, ul;
        ua.u4 = pfH[s % DEPTH];
        ul.u4 = pfL[s % DEPTH];
        if (s + DEPTH < NT) loadA(s % DEPTH, s + DEPTH);
        const short8 bh = *(const short8*)(G.wlh + G.boff + s*32);
        const short8 bl = *(const short8*)(G.wll + G.boff + s*32);
        acc = __builtin_amdgcn_mfma_f32_16x16x32_bf16(ua.s8, bh, acc, 0,0,0);
        acc = __builtin_amdgcn_mfma_f32_16x16x32_bf16(ul.s8, bh, acc, 0,0,0);
        acc = __builtin_amdgcn_mfma_f32_16x16x32_bf16(ua.s8, bl, acc, 0,0,0);
    }

    // C fragments -> LDS bounce
    {
        const int crow = G.Mtile*16 + G.aq*4;
        #pragma unroll
        for (int r = 0; r < 4; ++r)
            G.Cb[(crow + r)*33 + G.col_local] = acc[r];
    }
    __syncthreads();

    // gates + cell update + split-bf16 h store (CB8 layout, block-private)
    {
        float g4[4];
        #pragma unroll
        for (int g = 0; g < 4; ++g) g4[g] = G.Cb[G.erow*33 + g*8 + G.hcl] + G.bsum[g];
        const float gi = sigm(g4[0]), gf = sigm(g4[1]);
        const float gg = tanhfast(g4[2]), go = sigm(g4[3]);
        cr = gf*cr + gi*gg;
        const float h = go * tanhfast(cr);
        const u16 hh = bf16rn(h);
        const u16 hl = bf16rn(h - bf2f(hh));
        const size_t a = ((size_t)G.cg << 11) + (size_t)(G.mg*128 + G.erow)*8 + G.hcl;
        dH[a] = hh; dL[a] = hl;
    }
}

// ---------------------------------------------------------------------------
// Persistent MFMA LSTM. 256 blocks x 1024 threads (16 waves, 4/SIMD).
// Layer 1: blocks 0..127; layer 0: blocks 128..255. Block = (cg 0..63, mg
// 0..1): 32 gate-cols (8 h-cols = one cb8) x 128 batch rows. Weights
// split-bf16 LDS-resident. A read direct global->regs, depth-6 pipeline.
// ---------------------------------------------------------------------------
__global__ __launch_bounds__(THR, 1) void k_lstm(
    const u16* __restrict__ attnH, const u16* __restrict__ attnL,
    const float* __restrict__ Wx0, const float* __restrict__ bx0,
    u16* __restrict__ h0h, u16* __restrict__ h0l,
    u16* __restrict__ h1h, u16* __restrict__ h1l,
    const float* __restrict__ w_ih, const float* __restrict__ w_hh,
    const float* __restrict__ b_ih, const float* __restrict__ b_hh,
    const float* __restrict__ w_out, const float* __restrict__ b_out,
    float* __restrict__ out, int* __restrict__ bar)
{
    extern __shared__ char smem[];
    const int tid  = threadIdx.x;
    const int bx   = blockIdx.x;
    const bool lay1 = (bx < 128);
    const int idx  = lay1 ? bx : bx - 128;
    const int cg   = idx >> 1;
    const int mg   = idx & 1;
    const int KSTR = lay1 ? 1032 : 776;   // padded k-stride (halves)
    const int KW   = lay1 ? 1024 : 768;

    u16*   wlh = (u16*)smem;
    u16*   wll = wlh + 32*KSTR;
    float* Cb  = (float*)(smem + 132096);

    const int wid = tid >> 6, l = tid & 63;
    const int Mtile = wid & 7, Ntile = wid >> 3;
    const int lr = l & 15, aq = l >> 4;

    Geo G;
    G.wlh = wlh; G.wll = wll; G.Cb = Cb;
    G.rowg = mg*128 + Mtile*16 + lr;
    G.aq = aq;
    G.Mtile = Mtile;
    G.col_local = Ntile*16 + lr;
    G.boff = G.col_local*KSTR + aq*8;
    G.erow = tid & 127; G.hcl = tid >> 7;
    G.cg = cg; G.mg = mg;

    // ---- stage weights once: split fp32 -> bf16 hi/lo, k-major per col
    for (int c = 0; c < 32; ++c) {
        const int grow = (c >> 3)*HID + cg*8 + (c & 7);
        const float* src0; const float* src1; int klen0;
        if (lay1) {
            src0 = w_ih + (size_t)GATES*HID + (size_t)grow*HID; klen0 = 512;
            src1 = w_hh + (size_t)GATES*HID + (size_t)grow*HID;
        } else {
            src0 = Wx0 + (size_t)grow*FEATD;                    klen0 = 256;
            src1 = w_hh + (size_t)grow*HID;
        }
        for (int k = tid; k < KW; k += THR) {
            float f = (k < klen0) ? src0[k] : src1[k - klen0];
            u16 hi = bf16rn(f);
            wlh[c*KSTR + k] = hi;
            wll[c*KSTR + k] = bf16rn(f - bf2f(hi));
        }
    }

    float bsum[4];
    #pragma unroll
    for (int g = 0; g < 4; ++g) {
        const int gidx = g*HID + cg*8 + G.hcl;
        bsum[g] = lay1 ? (b_ih[GATES + gidx] + b_hh[GATES + gidx]) : bx0[gidx];
    }
    G.bsum = bsum;
    float cr = 0.f;
    __syncthreads();

    // projection: rows 2*idx, 2*idx+1 (layer-0 blocks only)
    auto proj = [&](const u16* hH, const u16* hL, int tout) {
        if (tid < 256) {
            const int r = tid >> 7, j = (tid >> 4) & 7, ks = tid & 15;
            const int n = 2*idx + r;
            float s = 0.f;
            #pragma unroll
            for (int kk = 0; kk < 32; ++kk) {
                const int k = ks*32 + kk;
                const size_t a = (size_t)(k >> 3)*2048 + (size_t)n*8 + (k & 7);
                float hv = bf2f(hH[a]) + bf2f(hL[a]);
                hv = hv > 0.f ? hv : 0.f;
                s += hv * w_out[(size_t)j*HID + k];
            }
            s += __shfl_xor(s, 1); s += __shfl_xor(s, 2);
            s += __shfl_xor(s, 4); s += __shfl_xor(s, 8);
            if (ks == 0)
                out[(size_t)n*(TOUT*NHEADS) + (size_t)tout*NHEADS + j] = s + b_out[j];
        }
    };

    // ---- prologue: layer0 computes h0(0) from attn(0) only
    if (!lay1)
        do_step<8,8>(G, attnH, attnL, attnH, attnL, h0h, h0l, cr);
    grid_bar(bar, 1*NBLK);

    // ---- pipelined: layer1(t) || layer0(t+1), t = 0..254
    for (int t = 0; t <= SEQT - 2; ++t) {
        if (lay1) {
            const int p = t & 1, q = p ^ 1;
            if (t == 0)
                do_step<16,16>(G, h0h + (size_t)p*BH, h0l + (size_t)p*BH,
                                  h1h + (size_t)q*BH, h1l + (size_t)q*BH,
                                  h1h + (size_t)p*BH, h1l + (size_t)p*BH, cr);
            else
                do_step<16,32>(G, h0h + (size_t)p*BH, h0l + (size_t)p*BH,
                                  h1h + (size_t)q*BH, h1l + (size_t)q*BH,
                                  h1h + (size_t)p*BH, h1l + (size_t)p*BH, cr);
        } else {
            if (t >= 1) {
                const int q = (t - 1) & 1;
                proj(h1h + (size_t)q*BH, h1l + (size_t)q*BH, t - 1);
            }
            if (t <= SEQT - 3) {
                const int tt = t + 1, p = t & 1, d = tt & 1;
                do_step<8,24>(G, attnH + (size_t)tt*65536, attnL + (size_t)tt*65536,
                                 h0h + (size_t)p*BH, h0l + (size_t)p*BH,
                                 h0h + (size_t)d*BH, h0l + (size_t)d*BH, cr);
            }
        }
        grid_bar(bar, (t + 2)*NBLK);
    }

    // ---- tail: project h1(254) (parity 0)
    if (!lay1) proj(h1h, h1l, TOUT - 1);
}

// ---------------------------------------------------------------------------
extern "C" void kernel_launch(void* const* d_in, const int* in_sizes, int n_in,
                              void* d_out, int out_size, void* d_ws, size_t ws_size,
                              hipStream_t stream)
{
    (void)in_sizes; (void)n_in; (void)out_size; (void)ws_size;
    const float* x     = (const float*)d_in[0];
    const float* wq    = (const float*)d_in[1];
    const float* wk    = (const float*)d_in[2];
    const float* wv    = (const float*)d_in[3];
    const float* w_fc  = (const float*)d_in[4];
    const float* b_fc  = (const float*)d_in[5];
    const float* w_hid = (const float*)d_in[6];
    const float* b_hid = (const float*)d_in[7];
    const float* w_ih  = (const float*)d_in[8];
    const float* w_hh  = (const float*)d_in[9];
    const float* b_ih  = (const float*)d_in[10];
    const float* b_hh  = (const float*)d_in[11];
    const float* w_out = (const float*)d_in[12];
    const float* b_out = (const float*)d_in[13];

    float* ws = (float*)d_ws;
    size_t off = 0;
    u16* attnH = (u16*)(ws + off); off += (size_t)SEQT*BATCH*FEATD/2;
    u16* attnL = (u16*)(ws + off); off += (size_t)SEQT*BATCH*FEATD/2;
    float* Wc  = ws + off; off += (size_t)HID*FEATD;
    float* bc  = ws + off; off += HID;
    float* Wx0 = ws + off; off += (size_t)GATES*FEATD;
    float* bx0 = ws + off; off += GATES;
    u16* h0h = (u16*)(ws + off); off += BH;    // 2 parity slabs (BH halves each)
    u16* h0l = (u16*)(ws + off); off += BH;
    u16* h1h = (u16*)(ws + off); off += BH;
    u16* h1l = (u16*)(ws + off); off += BH;
    int* bar = (int*)(ws + off); off += 64;

    hipMemsetAsync(bar, 0, sizeof(int), stream);

    k_attn  <<<dim3(BATCH*NHEADS), dim3(256), 0, stream>>>(x, wq, wk, wv, attnH, attnL);
    k_wcomb <<<dim3(HID),          dim3(256), 0, stream>>>(w_fc, b_fc, w_hid, b_hid, Wc, bc);
    k_wx0   <<<dim3(GATES),        dim3(256), 0, stream>>>(w_ih, Wc, bc, b_ih, b_hh, Wx0, bx0);

    const int shmem = 132096 + 128*33*4;   // weights (L1 max) + Cb = 148992 B
    (void)hipFuncSetAttribute(reinterpret_cast<const void*>(k_lstm),
                              hipFuncAttributeMaxDynamicSharedMemorySize, shmem);
    k_lstm <<<dim3(NBLK), dim3(THR), (size_t)shmem, stream>>>(
        attnH, attnL, Wx0, bx0, h0h, h0l, h1h, h1l,
        w_ih, w_hh, b_ih, b_hh, w_out, b_out, (float*)d_out, bar);
}